// Round 4
// baseline (77.802 us; speedup 1.0000x reference)
//
#include <hip/hip_runtime.h>

// SDF Chamfer loss, H=W=64, 2 images. Two kernels total.
// Points are compacted per 512-edge segment (gapped layout, 16 segs/imgset).
// ws float layout:
//   [0..63]    int cnt_seg[imgset*16+seg]
//   [64]       int done counter (zeroed by K1 each call)
//   [128..255] l1 partial sums (128, one per 64-px chunk)
//   [256..33023]   min d^2, gapped [imgset][16*512] (float bits, atomicMin)
//   [33024..]      points float2, gapped [imgset][16*512]
#define HH 64
#define WW 64
#define NV ((HH-1)*WW)        // 4032
#define NP (NV + HH*(WW-1))   // 8064
#define NSEG 16
#define SEGCAP 512
#define CAP (NSEG*SEGCAP)     // 8192 slots per imgset
#define EPSF 1e-8f
#define BIGF 3.0e38f
#define CNT_OFF 0
#define DONE_OFF 64
#define L1_OFF 128
#define MIN_OFF 256
#define PTS_OFF 33024

__device__ __forceinline__ void edge_point(const float* __restrict__ sdf, int e,
                                           float& R, float& C, bool& m) {
    float v1, v2;
    if (e < NV) {                       // vertical: rows i, i+1
        int i = e >> 6, j = e & 63;
        v1 = sdf[i * WW + j];
        v2 = sdf[i * WW + WW + j];
        float a = fabsf(v1) / (fabsf(v1) + fabsf(v2) + EPSF);
        float frac = (v1 == 0.f) ? 0.f : ((v2 == 0.f) ? 1.f : a);
        R = (float)i + frac; C = (float)j;
    } else {                            // horizontal: cols j, j+1
        int eh = e - NV;
        int i = eh / (WW - 1), j = eh % (WW - 1);
        v1 = sdf[i * WW + j];
        v2 = sdf[i * WW + j + 1];
        float a = fabsf(v1) / (fabsf(v1) + fabsf(v2) + EPSF);
        float frac = (v1 == 0.f) ? 0.f : ((v2 == 0.f) ? 1.f : a);
        R = (float)i; C = (float)j + frac;
    }
    m = (v1 == 0.f) || (v2 == 0.f) || (v1 * v2 < 0.f);
}

// grid: 64 blocks = imgset(4) x seg(16), 256 threads; 512 edges per block.
__global__ __launch_bounds__(256) void extract_kernel(const float* __restrict__ pred,
                                                      const float* __restrict__ gt,
                                                      float* __restrict__ ws) {
    int blk = blockIdx.x;
    int imgset = blk >> 4, seg = blk & 15;
    int b = imgset >> 1, set = imgset & 1;
    const float* sdf = (set == 0 ? pred : gt) + b * (HH * WW);
    int tid = threadIdx.x, lane = tid & 63, wid = tid >> 6;
    int base_e = seg * SEGCAP;

    float RA = 0, CA = 0, RB = 0, CB = 0; bool mA = false, mB = false;
    int eA = base_e + tid, eB = base_e + 256 + tid;
    if (eA < NP) edge_point(sdf, eA, RA, CA, mA);
    if (eB < NP) edge_point(sdf, eB, RB, CB, mB);

    unsigned long long bA = __ballot(mA), bB = __ballot(mB);
    __shared__ int wc0[4], wc1[4];
    if (lane == 0) { wc0[wid] = __popcll(bA); wc1[wid] = __popcll(bB); }

    // init this segment's min slots
    unsigned* minu = (unsigned*)(ws + MIN_OFF) + imgset * CAP + seg * SEGCAP;
    minu[tid] = __float_as_uint(BIGF);
    minu[tid + 256] = __float_as_uint(BIGF);
    __syncthreads();

    int offA = 0, offB = 0;
    for (int w = 0; w < wid; ++w) { offA += wc0[w]; offB += wc1[w]; }
    int c0 = wc0[0] + wc0[1] + wc0[2] + wc0[3];
    int cnt = c0 + wc1[0] + wc1[1] + wc1[2] + wc1[3];
    offB += c0;
    unsigned long long lt = (1ull << lane) - 1ull;
    float2* dst = (float2*)(ws + PTS_OFF) + imgset * CAP + seg * SEGCAP;
    if (mA) dst[offA + __popcll(bA & lt)] = make_float2(RA, CA);
    if (mB) dst[offB + __popcll(bB & lt)] = make_float2(RB, CB);
    if (tid == 0) ((int*)ws)[CNT_OFF + blk] = cnt;
    if (blk == 0 && tid == 0) ((int*)ws)[DONE_OFF] = 0;

    // L1: 128 pixels per block over flat [8192] (2 images)
    if (tid < 128) {
        int px = blk * 128 + tid;
        float s = fabsf(pred[px] - gt[px]);
        for (int o = 32; o; o >>= 1) s += __shfl_down(s, o, 64);
        if (lane == 0) ws[L1_OFF + blk * 2 + wid] = s;
    }
}

// grid: 1024 blocks = imgset(4) x qseg(16) x cslice(16), 256 threads.
// Last block to finish does the final reduction and writes out[0].
__global__ __launch_bounds__(256) void chamfer_kernel(float* __restrict__ ws,
                                                      float* __restrict__ out) {
    int blk = blockIdx.x;
    int imgset = blk >> 8;
    int qseg = (blk >> 4) & 15;
    int cslice = blk & 15;
    int tid = threadIdx.x, lane = tid & 63, wid = tid >> 6;
    const int* cnts = (const int*)ws;
    int qcnt = cnts[imgset * NSEG + qseg];
    int ccnt = cnts[(imgset ^ 1) * NSEG + cslice];

    __shared__ __align__(16) float2 tile[SEGCAP];
    const float2* csrc = (const float2*)(ws + PTS_OFF) + (imgset ^ 1) * CAP + cslice * SEGCAP;
    tile[tid]       = (tid       < ccnt) ? csrc[tid]       : make_float2(1e9f, 1e9f);
    tile[tid + 256] = (tid + 256 < ccnt) ? csrc[tid + 256] : make_float2(1e9f, 1e9f);
    __syncthreads();

    if (ccnt > 0 && qcnt > 0) {
        const float4* t4 = (const float4*)tile;
        unsigned* minq = (unsigned*)(ws + MIN_OFF) + imgset * CAP + qseg * SEGCAP;
        const float2* qsrc = (const float2*)(ws + PTS_OFF) + imgset * CAP + qseg * SEGCAP;
        int niter = (ccnt + 3) >> 2;
        int nb = (qcnt > 256) ? 2 : 1;
        for (int bq = 0; bq < nb; ++bq) {
            int q = bq * 256 + tid;
            if (q < qcnt) {
                float2 qp = qsrc[q];
                float m0 = BIGF, m1 = BIGF, m2 = BIGF, m3 = BIGF;
                for (int k = 0; k < niter; ++k) {
                    float4 a = t4[2 * k];
                    float4 c = t4[2 * k + 1];
                    float dx0 = qp.x - a.x, dy0 = qp.y - a.y;
                    float dx1 = qp.x - a.z, dy1 = qp.y - a.w;
                    float dx2 = qp.x - c.x, dy2 = qp.y - c.y;
                    float dx3 = qp.x - c.z, dy3 = qp.y - c.w;
                    m0 = fminf(m0, __builtin_fmaf(dx0, dx0, dy0 * dy0));
                    m1 = fminf(m1, __builtin_fmaf(dx1, dx1, dy1 * dy1));
                    m2 = fminf(m2, __builtin_fmaf(dx2, dx2, dy2 * dy2));
                    m3 = fminf(m3, __builtin_fmaf(dx3, dx3, dy3 * dy3));
                }
                float m = fminf(fminf(m0, m1), fminf(m2, m3));
                atomicMin(&minq[q], __float_as_uint(m));   // exact for d2 >= 0
            }
        }
    }

    // last-block-done finalize
    __syncthreads();
    __shared__ int lastflag;
    if (tid == 0) {
        __threadfence();
        lastflag = (atomicAdd((int*)ws + DONE_OFF, 1) == (int)gridDim.x - 1);
    }
    __syncthreads();
    if (!lastflag) return;
    __threadfence();

    __shared__ float red[4];
    __shared__ float sums[4];
    for (int d = 0; d < 4; ++d) {
        float s = 0.f;
        const unsigned* mind = (const unsigned*)(ws + MIN_OFF) + d * CAP;
        for (int idx = tid; idx < CAP; idx += 256) {
            int pos = idx & (SEGCAP - 1);
            int sg = idx >> 9;
            if (pos < cnts[d * NSEG + sg]) {
                unsigned bits = __hip_atomic_load(&mind[idx], __ATOMIC_RELAXED,
                                                  __HIP_MEMORY_SCOPE_AGENT);
                s += sqrtf(__uint_as_float(bits));
            }
        }
        for (int o = 32; o; o >>= 1) s += __shfl_down(s, o, 64);
        __syncthreads();
        if (lane == 0) red[wid] = s;
        __syncthreads();
        if (tid == 0) sums[d] = red[0] + red[1] + red[2] + red[3];
    }

    // l1: partial p covers px [p*64,p*64+64); img = p>>6
    float v = (tid < 128) ? ws[L1_OFF + tid] : 0.f;
    float s0 = (tid < 64) ? v : 0.f;
    float s1 = (tid >= 64 && tid < 128) ? v : 0.f;
    for (int o = 32; o; o >>= 1) { s0 += __shfl_down(s0, o, 64); s1 += __shfl_down(s1, o, 64); }
    __syncthreads();
    __shared__ float l1r[8];
    if (lane == 0) { l1r[wid] = s0; l1r[4 + wid] = s1; }
    __syncthreads();
    if (tid == 0) {
        float l1a = l1r[0] + l1r[1] + l1r[2] + l1r[3];
        float l1b = l1r[4] + l1r[5] + l1r[6] + l1r[7];
        float loss = 0.f;
        for (int b = 0; b < 2; ++b) {
            int ct0 = 0, ct1 = 0;
            for (int sg = 0; sg < NSEG; ++sg) {
                ct0 += cnts[(b * 2 + 0) * NSEG + sg];
                ct1 += cnts[(b * 2 + 1) * NSEG + sg];
            }
            float mean1 = sums[b * 2 + 0] / fmaxf((float)ct0, 1.f);   // pred->gt
            float mean2 = sums[b * 2 + 1] / fmaxf((float)ct1, 1.f);   // gt->pred
            float cd = -mean1 + mean2;
            float l1m = (b == 0 ? l1a : l1b) * (1.f / (HH * WW));
            loss += l1m + fabsf(cd);
        }
        out[0] = loss * 0.5f;
    }
}

extern "C" void kernel_launch(void* const* d_in, const int* in_sizes, int n_in,
                              void* d_out, int out_size, void* d_ws, size_t ws_size,
                              hipStream_t stream) {
    const float* pred = (const float*)d_in[0];
    const float* gt   = (const float*)d_in[1];
    float* ws  = (float*)d_ws;
    float* out = (float*)d_out;

    hipLaunchKernelGGL(extract_kernel, dim3(64),   dim3(256), 0, stream, pred, gt, ws);
    hipLaunchKernelGGL(chamfer_kernel, dim3(1024), dim3(256), 0, stream, ws, out);
}

// Round 5
// 42.347 us; speedup vs baseline: 1.8373x; 1.8373x over previous
//
#include <hip/hip_runtime.h>

// SDF Chamfer loss, H=W=64, 2 images. Three kernels, no fences, no hot atomics.
// Points compacted per 512-edge segment (gapped layout, 16 segs per imgset).
// ws float layout:
//   [0..63]        int cnt_seg[imgset*16+seg]
//   [256..33023]   min d^2, gapped [imgset][16*512] (float bits; uint atomicMin)
//   [33024..]      points float2, gapped [imgset][16*512]
#define HH 64
#define WW 64
#define NV ((HH-1)*WW)        // 4032
#define NP (NV + HH*(WW-1))   // 8064
#define NSEG 16
#define SEGCAP 512
#define CAP (NSEG*SEGCAP)     // 8192 slots per imgset
#define EPSF 1e-8f
#define BIGF 3.0e38f
#define CNT_OFF 0
#define MIN_OFF 256
#define PTS_OFF 33024

__device__ __forceinline__ void edge_point(const float* __restrict__ sdf, int e,
                                           float& R, float& C, bool& m) {
    float v1, v2;
    if (e < NV) {                       // vertical: rows i, i+1
        int i = e >> 6, j = e & 63;
        v1 = sdf[i * WW + j];
        v2 = sdf[i * WW + WW + j];
        float a = fabsf(v1) / (fabsf(v1) + fabsf(v2) + EPSF);
        float frac = (v1 == 0.f) ? 0.f : ((v2 == 0.f) ? 1.f : a);
        R = (float)i + frac; C = (float)j;
    } else {                            // horizontal: cols j, j+1
        int eh = e - NV;
        int i = eh / (WW - 1), j = eh % (WW - 1);
        v1 = sdf[i * WW + j];
        v2 = sdf[i * WW + j + 1];
        float a = fabsf(v1) / (fabsf(v1) + fabsf(v2) + EPSF);
        float frac = (v1 == 0.f) ? 0.f : ((v2 == 0.f) ? 1.f : a);
        R = (float)i; C = (float)j + frac;
    }
    m = (v1 == 0.f) || (v2 == 0.f) || (v1 * v2 < 0.f);
}

// grid: 64 blocks = imgset(4) x seg(16), 256 threads; 512 edges per block.
__global__ __launch_bounds__(256) void extract_kernel(const float* __restrict__ pred,
                                                      const float* __restrict__ gt,
                                                      float* __restrict__ ws) {
    int blk = blockIdx.x;
    int imgset = blk >> 4, seg = blk & 15;
    int b = imgset >> 1, set = imgset & 1;
    const float* sdf = (set == 0 ? pred : gt) + b * (HH * WW);
    int tid = threadIdx.x, lane = tid & 63, wid = tid >> 6;
    int base_e = seg * SEGCAP;

    float RA = 0, CA = 0, RB = 0, CB = 0; bool mA = false, mB = false;
    int eA = base_e + tid, eB = base_e + 256 + tid;
    if (eA < NP) edge_point(sdf, eA, RA, CA, mA);
    if (eB < NP) edge_point(sdf, eB, RB, CB, mB);

    unsigned long long bA = __ballot(mA), bB = __ballot(mB);
    __shared__ int wc0[4], wc1[4];
    if (lane == 0) { wc0[wid] = __popcll(bA); wc1[wid] = __popcll(bB); }

    // init this segment's min slots (re-done every call -> deterministic)
    unsigned* minu = (unsigned*)(ws + MIN_OFF) + imgset * CAP + seg * SEGCAP;
    minu[tid] = __float_as_uint(BIGF);
    minu[tid + 256] = __float_as_uint(BIGF);
    __syncthreads();

    int offA = 0, offB = 0;
    for (int w = 0; w < wid; ++w) { offA += wc0[w]; offB += wc1[w]; }
    int c0 = wc0[0] + wc0[1] + wc0[2] + wc0[3];
    int cnt = c0 + wc1[0] + wc1[1] + wc1[2] + wc1[3];
    offB += c0;
    unsigned long long lt = (1ull << lane) - 1ull;
    float2* dst = (float2*)(ws + PTS_OFF) + imgset * CAP + seg * SEGCAP;
    if (mA) dst[offA + __popcll(bA & lt)] = make_float2(RA, CA);
    if (mB) dst[offB + __popcll(bB & lt)] = make_float2(RB, CB);
    if (tid == 0) ((int*)ws)[CNT_OFF + blk] = cnt;
}

// grid: 1024 blocks = imgset(4) x qseg(16) x cslice(16), 256 threads.
// Distributed-address atomicMin only; no counters, no fences.
__global__ __launch_bounds__(256) void chamfer_kernel(float* __restrict__ ws) {
    int blk = blockIdx.x;
    int imgset = blk >> 8;
    int qseg = (blk >> 4) & 15;
    int cslice = blk & 15;
    int tid = threadIdx.x;
    const int* cnts = (const int*)ws;
    int qcnt = cnts[imgset * NSEG + qseg];
    int ccnt = cnts[(imgset ^ 1) * NSEG + cslice];
    if (qcnt <= 0 || ccnt <= 0) return;

    __shared__ __align__(16) float2 tile[SEGCAP];
    const float2* csrc = (const float2*)(ws + PTS_OFF) + (imgset ^ 1) * CAP + cslice * SEGCAP;
    tile[tid]       = (tid       < ccnt) ? csrc[tid]       : make_float2(1e9f, 1e9f);
    tile[tid + 256] = (tid + 256 < ccnt) ? csrc[tid + 256] : make_float2(1e9f, 1e9f);
    __syncthreads();

    const float4* t4 = (const float4*)tile;
    unsigned* minq = (unsigned*)(ws + MIN_OFF) + imgset * CAP + qseg * SEGCAP;
    const float2* qsrc = (const float2*)(ws + PTS_OFF) + imgset * CAP + qseg * SEGCAP;
    int niter = (ccnt + 3) >> 2;
    int nb = (qcnt > 256) ? 2 : 1;
    for (int bq = 0; bq < nb; ++bq) {
        int q = bq * 256 + tid;
        if (q < qcnt) {
            float2 qp = qsrc[q];
            float m0 = BIGF, m1 = BIGF, m2 = BIGF, m3 = BIGF;
            for (int k = 0; k < niter; ++k) {
                float4 a = t4[2 * k];
                float4 c = t4[2 * k + 1];
                float dx0 = qp.x - a.x, dy0 = qp.y - a.y;
                float dx1 = qp.x - a.z, dy1 = qp.y - a.w;
                float dx2 = qp.x - c.x, dy2 = qp.y - c.y;
                float dx3 = qp.x - c.z, dy3 = qp.y - c.w;
                m0 = fminf(m0, __builtin_fmaf(dx0, dx0, dy0 * dy0));
                m1 = fminf(m1, __builtin_fmaf(dx1, dx1, dy1 * dy1));
                m2 = fminf(m2, __builtin_fmaf(dx2, dx2, dy2 * dy2));
                m3 = fminf(m3, __builtin_fmaf(dx3, dx3, dy3 * dy3));
            }
            float m = fminf(fminf(m0, m1), fminf(m2, m3));
            atomicMin(&minq[q], __float_as_uint(m));   // exact: d2 >= 0
        }
    }
}

__device__ __forceinline__ float block_sum_1024(float v) {
    __shared__ float red[16];
    int lane = threadIdx.x & 63, wid = threadIdx.x >> 6;
    for (int o = 32; o; o >>= 1) v += __shfl_down(v, o, 64);
    __syncthreads();                 // guard red against previous use
    if (lane == 0) red[wid] = v;
    __syncthreads();
    if (wid == 0) {
        v = (lane < 16) ? red[lane] : 0.f;
        for (int o = 8; o; o >>= 1) v += __shfl_down(v, o, 64);
    }
    return v;   // valid in thread 0
}

// 1 block, 1024 threads: sqrt-sums of mins + L1 recompute + final loss.
__global__ __launch_bounds__(1024) void tail_kernel(const float* __restrict__ ws,
                                                    const float* __restrict__ pred,
                                                    const float* __restrict__ gt,
                                                    float* __restrict__ out) {
    const int* cnts = (const int*)ws;
    int tid = threadIdx.x;
    __shared__ float sums[4];

    for (int d = 0; d < 4; ++d) {
        float s = 0.f;
        const float* mind = ws + MIN_OFF + d * CAP;
        for (int idx = tid; idx < CAP; idx += 1024) {
            int sg = idx >> 9, pos = idx & (SEGCAP - 1);
            if (pos < cnts[d * NSEG + sg]) s += sqrtf(mind[idx]);
        }
        float r = block_sum_1024(s);
        if (tid == 0) sums[d] = r;
    }

    // L1 terms straight from inputs: 2048 float4 spans both images
    const float4* p4 = (const float4*)pred;
    const float4* g4 = (const float4*)gt;
    float4 a = p4[tid], b4 = g4[tid];                    // img0: px 4t..4t+3
    float s0 = fabsf(a.x - b4.x) + fabsf(a.y - b4.y) + fabsf(a.z - b4.z) + fabsf(a.w - b4.w);
    a = p4[1024 + tid]; b4 = g4[1024 + tid];             // img1
    float s1 = fabsf(a.x - b4.x) + fabsf(a.y - b4.y) + fabsf(a.z - b4.z) + fabsf(a.w - b4.w);
    float r0 = block_sum_1024(s0);
    float r1 = block_sum_1024(s1);

    if (tid == 0) {
        int ct[4] = {0, 0, 0, 0};
        for (int sg = 0; sg < NSEG; ++sg)
            for (int d = 0; d < 4; ++d) ct[d] += cnts[d * NSEG + sg];
        float l1s[2] = {r0, r1};
        float loss = 0.f;
        for (int b = 0; b < 2; ++b) {
            float mean1 = sums[2 * b + 0] / fmaxf((float)ct[2 * b + 0], 1.f); // pred->gt
            float mean2 = sums[2 * b + 1] / fmaxf((float)ct[2 * b + 1], 1.f); // gt->pred
            loss += l1s[b] * (1.f / (HH * WW)) + fabsf(-mean1 + mean2);
        }
        out[0] = loss * 0.5f;
    }
}

extern "C" void kernel_launch(void* const* d_in, const int* in_sizes, int n_in,
                              void* d_out, int out_size, void* d_ws, size_t ws_size,
                              hipStream_t stream) {
    const float* pred = (const float*)d_in[0];
    const float* gt   = (const float*)d_in[1];
    float* ws  = (float*)d_ws;
    float* out = (float*)d_out;

    hipLaunchKernelGGL(extract_kernel, dim3(64),   dim3(256),  0, stream, pred, gt, ws);
    hipLaunchKernelGGL(chamfer_kernel, dim3(1024), dim3(256),  0, stream, ws);
    hipLaunchKernelGGL(tail_kernel,    dim3(1),    dim3(1024), 0, stream, ws, pred, gt, out);
}

// Round 6
// 30.898 us; speedup vs baseline: 2.5180x; 1.3705x over previous
//
#include <hip/hip_runtime.h>

// SDF Chamfer loss, H=W=64, 2 images. Three kernels, zero atomics, no min array.
// ws float layout:
//   [0..63]     int cnt_seg[imgset*16+seg]
//   [64..319]   chamfer partial sums, one per K2 block (256)
//   [1024..]    compacted points float2, gapped [imgset][16*512]
#define HH 64
#define WW 64
#define NV ((HH-1)*WW)        // 4032
#define NP (NV + HH*(WW-1))   // 8064
#define NSEG 16
#define SEGCAP 512
#define CAP (NSEG*SEGCAP)     // 8192 slots per imgset
#define EPSF 1e-8f
#define BIGF 3.0e38f
#define CNT_OFF 0
#define PART_OFF 64
#define PTS_OFF 1024

__device__ __forceinline__ void edge_point(const float* __restrict__ sdf, int e,
                                           float& R, float& C, bool& m) {
    float v1, v2;
    if (e < NV) {                       // vertical: rows i, i+1
        int i = e >> 6, j = e & 63;
        v1 = sdf[i * WW + j];
        v2 = sdf[i * WW + WW + j];
        float a = fabsf(v1) / (fabsf(v1) + fabsf(v2) + EPSF);
        float frac = (v1 == 0.f) ? 0.f : ((v2 == 0.f) ? 1.f : a);
        R = (float)i + frac; C = (float)j;
    } else {                            // horizontal: cols j, j+1
        int eh = e - NV;
        int i = eh / (WW - 1), j = eh % (WW - 1);
        v1 = sdf[i * WW + j];
        v2 = sdf[i * WW + j + 1];
        float a = fabsf(v1) / (fabsf(v1) + fabsf(v2) + EPSF);
        float frac = (v1 == 0.f) ? 0.f : ((v2 == 0.f) ? 1.f : a);
        R = (float)i; C = (float)j + frac;
    }
    m = (v1 == 0.f) || (v2 == 0.f) || (v1 * v2 < 0.f);
}

// grid: 64 blocks = imgset(4) x seg(16), 256 threads; 512 edges per block.
__global__ __launch_bounds__(256) void extract_kernel(const float* __restrict__ pred,
                                                      const float* __restrict__ gt,
                                                      float* __restrict__ ws) {
    int blk = blockIdx.x;
    int imgset = blk >> 4, seg = blk & 15;
    int b = imgset >> 1, set = imgset & 1;
    const float* sdf = (set == 0 ? pred : gt) + b * (HH * WW);
    int tid = threadIdx.x, lane = tid & 63, wid = tid >> 6;
    int base_e = seg * SEGCAP;

    float RA = 0, CA = 0, RB = 0, CB = 0; bool mA = false, mB = false;
    int eA = base_e + tid, eB = base_e + 256 + tid;
    if (eA < NP) edge_point(sdf, eA, RA, CA, mA);
    if (eB < NP) edge_point(sdf, eB, RB, CB, mB);

    unsigned long long bA = __ballot(mA), bB = __ballot(mB);
    __shared__ int wc0[4], wc1[4];
    if (lane == 0) { wc0[wid] = __popcll(bA); wc1[wid] = __popcll(bB); }
    __syncthreads();

    int offA = 0, offB = 0;
    for (int w = 0; w < wid; ++w) { offA += wc0[w]; offB += wc1[w]; }
    int c0 = wc0[0] + wc0[1] + wc0[2] + wc0[3];
    int cnt = c0 + wc1[0] + wc1[1] + wc1[2] + wc1[3];
    offB += c0;
    unsigned long long lt = (1ull << lane) - 1ull;
    float2* dst = (float2*)(ws + PTS_OFF) + imgset * CAP + seg * SEGCAP;
    if (mA) dst[offA + __popcll(bA & lt)] = make_float2(RA, CA);
    if (mB) dst[offB + __popcll(bB & lt)] = make_float2(RB, CB);
    if (tid == 0) ((int*)ws)[CNT_OFF + blk] = cnt;
}

// grid: 256 blocks = imgset(4) x subq(64), 512 threads.
// Stage entire compacted candidate set in LDS; per-query min in registers
// (8 threads/query, shfl_xor combine); emit one partial sum per block.
__global__ __launch_bounds__(512) void chamfer_kernel(float* __restrict__ ws) {
    int blk = blockIdx.x;
    int imgset = blk >> 6;
    int subq = blk & 63;
    int tid = threadIdx.x, lane = tid & 63, wid = tid >> 6;
    const int* cnts = (const int*)ws;
    int copp = imgset ^ 1;

    __shared__ __align__(16) float2 ctile[CAP + 32];
    const float2* csrc = (const float2*)(ws + PTS_OFF) + copp * CAP;

    // gather gapped segments into contiguous ctile (compile-time s -> regs only)
    int ccnt = 0;
    #pragma unroll
    for (int s = 0; s < 16; ++s) {
        int c = cnts[copp * NSEG + s];
        if (tid < c) ctile[ccnt + tid] = csrc[s * SEGCAP + tid];
        ccnt += c;
    }
    int P2 = (ccnt + 31) & ~31;                       // pad to float4-pair x16
    for (int i = ccnt + tid; i < P2; i += 512) ctile[i] = make_float2(1e9f, 1e9f);

    // this block's query range: quarter of gapped segment sq
    int sq = subq >> 2, qt = subq & 3;
    int qc = cnts[imgset * NSEG + sq];
    int qq = (qc + 3) >> 2;
    int qlo = qt * qq, qhi = min(qc, qlo + qq);       // <=128 queries
    const float2* qsrc = (const float2*)(ws + PTS_OFF) + imgset * CAP + sq * SEGCAP;

    __syncthreads();

    int slot = tid >> 3, r = tid & 7;                 // 64 slots x 8 threads
    const float4* t4 = (const float4*)ctile;
    int kmax = P2 >> 5;
    float acc = 0.f;
    for (int pass = 0; pass < 2; ++pass) {
        if (pass == 1 && qhi - qlo <= 64) break;      // block-uniform
        int q = qlo + pass * 64 + slot;
        bool v = q < qhi;
        float2 qp = v ? qsrc[q] : make_float2(1e8f, 1e8f);
        float m0 = BIGF, m1 = BIGF, m2 = BIGF, m3 = BIGF;
        for (int k = 0; k < kmax; ++k) {              // 4 candidates/iter
            float4 a = t4[k * 16 + r];
            float4 c = t4[k * 16 + 8 + r];
            float dx0 = qp.x - a.x, dy0 = qp.y - a.y;
            float dx1 = qp.x - a.z, dy1 = qp.y - a.w;
            float dx2 = qp.x - c.x, dy2 = qp.y - c.y;
            float dx3 = qp.x - c.z, dy3 = qp.y - c.w;
            m0 = fminf(m0, __builtin_fmaf(dx0, dx0, dy0 * dy0));
            m1 = fminf(m1, __builtin_fmaf(dx1, dx1, dy1 * dy1));
            m2 = fminf(m2, __builtin_fmaf(dx2, dx2, dy2 * dy2));
            m3 = fminf(m3, __builtin_fmaf(dx3, dx3, dy3 * dy3));
        }
        float m = fminf(fminf(m0, m1), fminf(m2, m3));
        m = fminf(m, __shfl_xor(m, 1, 64));           // combine 8 r-lanes
        m = fminf(m, __shfl_xor(m, 2, 64));
        m = fminf(m, __shfl_xor(m, 4, 64));
        if (v && r == 0) acc += sqrtf(m);
    }

    // block sum over 512 threads
    for (int o = 32; o; o >>= 1) acc += __shfl_down(acc, o, 64);
    __shared__ float red[8];
    if (lane == 0) red[wid] = acc;
    __syncthreads();
    if (tid == 0) {
        float s = 0.f;
        for (int w = 0; w < 8; ++w) s += red[w];
        ws[PART_OFF + blk] = s;
    }
}

// 1 block, 256 threads: combine partials + counts + L1 + final loss.
__global__ __launch_bounds__(256) void tail_kernel(const float* __restrict__ ws,
                                                   const float* __restrict__ pred,
                                                   const float* __restrict__ gt,
                                                   float* __restrict__ out) {
    int tid = threadIdx.x, lane = tid & 63, wid = tid >> 6;
    const int* cnts = (const int*)ws;
    __shared__ float sums[4];
    __shared__ int ct[4];
    __shared__ float red[8];

    // chamfer sums: wave w owns imgset w's 64 partials
    float v = ws[PART_OFF + wid * 64 + lane];
    for (int o = 32; o; o >>= 1) v += __shfl_down(v, o, 64);
    if (lane == 0) sums[wid] = v;

    // counts: threads 0..63, 16-lane group per imgset
    if (tid < 64) {
        int c = cnts[tid];
        for (int o = 8; o; o >>= 1) c += __shfl_down(c, o, 16);
        if ((tid & 15) == 0) ct[tid >> 4] = c;
    }

    // L1 from inputs: 2048 float4 spans both images (1024 per image)
    const float4* p4 = (const float4*)pred;
    const float4* g4 = (const float4*)gt;
    float s0 = 0.f, s1 = 0.f;
    #pragma unroll
    for (int j = 0; j < 8; ++j) {
        int idx = tid + j * 256;
        float4 a = p4[idx], b = g4[idx];
        float t = fabsf(a.x - b.x) + fabsf(a.y - b.y) + fabsf(a.z - b.z) + fabsf(a.w - b.w);
        if (j < 4) s0 += t; else s1 += t;
    }
    for (int o = 32; o; o >>= 1) { s0 += __shfl_down(s0, o, 64); s1 += __shfl_down(s1, o, 64); }
    __syncthreads();
    if (lane == 0) { red[wid] = s0; red[4 + wid] = s1; }
    __syncthreads();

    if (tid == 0) {
        float l1a = red[0] + red[1] + red[2] + red[3];
        float l1b = red[4] + red[5] + red[6] + red[7];
        float loss = 0.f;
        for (int b = 0; b < 2; ++b) {
            float mean1 = sums[2 * b + 0] / fmaxf((float)ct[2 * b + 0], 1.f); // pred->gt
            float mean2 = sums[2 * b + 1] / fmaxf((float)ct[2 * b + 1], 1.f); // gt->pred
            loss += (b == 0 ? l1a : l1b) * (1.f / (HH * WW)) + fabsf(-mean1 + mean2);
        }
        out[0] = loss * 0.5f;
    }
}

extern "C" void kernel_launch(void* const* d_in, const int* in_sizes, int n_in,
                              void* d_out, int out_size, void* d_ws, size_t ws_size,
                              hipStream_t stream) {
    const float* pred = (const float*)d_in[0];
    const float* gt   = (const float*)d_in[1];
    float* ws  = (float*)d_ws;
    float* out = (float*)d_out;

    hipLaunchKernelGGL(extract_kernel, dim3(64),  dim3(256), 0, stream, pred, gt, ws);
    hipLaunchKernelGGL(chamfer_kernel, dim3(256), dim3(512), 0, stream, ws);
    hipLaunchKernelGGL(tail_kernel,    dim3(1),   dim3(256), 0, stream, ws, pred, gt, out);
}